// Round 15
// baseline (400.682 us; speedup 1.0000x reference)
//
#include <hip/hip_runtime.h>
#include <math.h>

#define S_ 1024
#define D_ 1024
#define H_ 16
#define F_ 4096

typedef short s16x8 __attribute__((ext_vector_type(8)));
typedef float fx4 __attribute__((ext_vector_type(4)));

__device__ __forceinline__ float bf2f(unsigned int u){
  union { float f; unsigned int u; } v; v.u = u<<16; return v.f;
}
__device__ __forceinline__ unsigned short f2bf(float f){
  union { float f; unsigned int u; } v; v.f = f;
  unsigned int r = v.u + 0x7fffu + ((v.u>>16)&1u);
  return (unsigned short)(r>>16);
}
__device__ __forceinline__ unsigned int pk2(float a, float b){
  return (unsigned int)f2bf(a) | ((unsigned int)f2bf(b)<<16);
}
__device__ __forceinline__ void gld16(const void* g, void* l){
  typedef const unsigned int __attribute__((address_space(1)))* gp_t;
  typedef unsigned int __attribute__((address_space(3)))* lp_t;
  __builtin_amdgcn_global_load_lds((gp_t)g, (lp_t)l, 16, 0, 0);
}
__device__ __forceinline__ int xcd_swz(int bid, int nwg){
  int q = nwg >> 3;
  return (bid & 7)*q + (bid >> 3);
}

// ---------------- rmsnorm: f32 [S,D] -> bf16 [S,D] ----------------
__global__ __launch_bounds__(256) void k_rmsnorm(const float* __restrict__ x, unsigned short* __restrict__ y){
  int row = blockIdx.x, t = threadIdx.x;
  const float4 v = ((const float4*)(x + (size_t)row*D_))[t];
  float ss = v.x*v.x + v.y*v.y + v.z*v.z + v.w*v.w;
  #pragma unroll
  for(int o=1;o<64;o<<=1) ss += __shfl_xor(ss, o);
  __shared__ float red[4];
  if((t&63)==0) red[t>>6]=ss;
  __syncthreads();
  float sc = rsqrtf((red[0]+red[1]+red[2]+red[3])*(1.0f/D_) + 1e-6f);
  ushort4 o4;
  o4.x=f2bf(v.x*sc); o4.y=f2bf(v.y*sc); o4.z=f2bf(v.z*sc); o4.w=f2bf(v.w*sc);
  ((ushort4*)(y + (size_t)row*D_))[t]=o4;
}

// ---------------- prep: abs_t[h][l][d]; wuvt[h][d][l] ----------------
__global__ __launch_bounds__(256) void k_prep(const float* __restrict__ Wq,
    const float* __restrict__ Wuk, const float* __restrict__ Wuv,
    float* __restrict__ abs_t, float* __restrict__ wuvt){
  int h = blockIdx.x, tid = threadIdx.x;
  __shared__ float wq[4096], wuk[4096];
  for(int i=tid;i<4096;i+=256){ wq[i]=Wq[h*4096+i]; wuk[i]=Wuk[h*4096+i]; }
  __syncthreads();
  for(int i=tid;i<4096;i+=256){
    float a=0.f;
    #pragma unroll 8
    for(int e=0;e<64;e++) a += wq[(i&63)*64+e]*wuk[(i>>6)*64+e];
    abs_t[h*4096+i]=a;
    wuvt[h*4096+i]=Wuv[h*4096 + (i&63)*64 + (i>>6)];
  }
}

// ---------------- MFMA projection helpers ----------------
__device__ __forceinline__ void stage_B64(const float* __restrict__ W, unsigned short* Bs, int tid){
  int n = tid>>2, kq = tid&3;
  const float* s = W + n*64 + kq*16;
  float4 f0=*(const float4*)(s), f1=*(const float4*)(s+4), f2=*(const float4*)(s+8), f3=*(const float4*)(s+12);
  ushort4 u0,u1,u2,u3;
  u0.x=f2bf(f0.x);u0.y=f2bf(f0.y);u0.z=f2bf(f0.z);u0.w=f2bf(f0.w);
  u1.x=f2bf(f1.x);u1.y=f2bf(f1.y);u1.z=f2bf(f1.z);u1.w=f2bf(f1.w);
  u2.x=f2bf(f2.x);u2.y=f2bf(f2.y);u2.z=f2bf(f2.z);u2.w=f2bf(f2.w);
  u3.x=f2bf(f3.x);u3.y=f2bf(f3.y);u3.z=f2bf(f3.z);u3.w=f2bf(f3.w);
  int sl0=((kq*2)^(n&7))*8, sl1=((kq*2+1)^(n&7))*8;
  *(ushort4*)&Bs[n*64+sl0]=u0;   *(ushort4*)&Bs[n*64+sl0+4]=u1;
  *(ushort4*)&Bs[n*64+sl1]=u2;   *(ushort4*)&Bs[n*64+sl1+4]=u3;
}
__device__ __forceinline__ void gemm64(const unsigned short* Asrc, const unsigned short* Bs,
    int wv, int l16, int l4, fx4 acc[4]){
  int srow = wv*16 + l16;
  #pragma unroll
  for(int kb=0;kb<2;kb++){
    s16x8 af = *(const s16x8*)&Asrc[srow*64 + (((kb*4+l4)^(srow&7))*8)];
    #pragma unroll
    for(int nf=0;nf<4;nf++){
      int n = nf*16+l16;
      s16x8 bf = *(const s16x8*)&Bs[n*64 + (((kb*4+l4)^(n&7))*8)];
      acc[nf] = __builtin_amdgcn_mfma_f32_16x16x32_bf16(af, bf, acc[nf], 0,0,0);
    }
  }
}

// ---------------- per-head projections via MFMA ----------------
__global__ __launch_bounds__(256) void k_proj_m(const unsigned short* __restrict__ y,
    const float* __restrict__ abs_t, const float* __restrict__ wuvt,
    const float* __restrict__ Wdkv, const float* __restrict__ Wk_rope,
    const float* __restrict__ Wq_rope, const float* __restrict__ bq_rope,
    unsigned short* __restrict__ kk, unsigned short* __restrict__ qq,
    unsigned short* __restrict__ vv){
  __shared__ unsigned short ysd[4096];
  __shared__ unsigned short ckvs[4096];
  __shared__ unsigned short Bs[4096];
  __shared__ unsigned short tmp[64*72];
  const float LNC = 0.28782313662425575f;
  const float ASC = 0.08838834764831845f;
  int s0 = blockIdx.x*64, h = blockIdx.y, tid = threadIdx.x;
  int wv = tid>>6, lane = tid&63, l16 = lane&15, l4 = lane>>4;
  fx4 acc[4];

  {
    int rg = lane>>3, sg = (lane&7)^(rg&7);
    #pragma unroll
    for(int c2=0;c2<2;c2++){
      int c = wv*2+c2;
      gld16(y + (size_t)(s0+c*8+rg)*D_ + h*64 + sg*8, &ysd[c*512]);
    }
  }
  stage_B64(Wdkv + h*4096, Bs, tid);
  __syncthreads();

  #pragma unroll
  for(int nf=0;nf<4;nf++){acc[nf][0]=0.f;acc[nf][1]=0.f;acc[nf][2]=0.f;acc[nf][3]=0.f;}
  gemm64(ysd, Bs, wv, l16, l4, acc);
  #pragma unroll
  for(int nf=0;nf<4;nf++){
    int col = nf*16+l16;
    #pragma unroll
    for(int r=0;r<4;r++){
      int srow = wv*16+4*l4+r;
      ckvs[srow*64 + (((col>>3)^(srow&7))*8) + (col&7)] = f2bf(acc[nf][r]);
    }
  }
  __syncthreads();
  { int row=tid>>2, sl=(tid&3)*2;
    uint4 a=*(const uint4*)&ckvs[row*64+sl*8];
    uint4 b=*(const uint4*)&ckvs[row*64+sl*8+8];
    unsigned short* kr = kk + ((size_t)(h*S_)+s0+row)*128;
    *(uint4*)&kr[(sl^(row&7))*8]=a;
    *(uint4*)&kr[((sl+1)^(row&7))*8]=b;
  }
  stage_B64(Wk_rope + h*4096, Bs, tid);
  __syncthreads();

  #pragma unroll
  for(int nf=0;nf<4;nf++){acc[nf][0]=0.f;acc[nf][1]=0.f;acc[nf][2]=0.f;acc[nf][3]=0.f;}
  gemm64(ysd, Bs, wv, l16, l4, acc);
  #pragma unroll
  for(int nf=0;nf<2;nf++){
    int llo = nf*16+l16;
    float inv = __expf(-(float)llo * LNC);
    #pragma unroll
    for(int r=0;r<4;r++){
      int srow = wv*16+4*l4+r;
      float sn,cs; __sincosf((float)(s0+srow)*inv,&sn,&cs);
      float alo=acc[nf][r], ahi=acc[nf+2][r];
      tmp[srow*72 + llo]      = f2bf(alo*cs - ahi*sn);
      tmp[srow*72 + llo + 32] = f2bf(ahi*cs + alo*sn);
    }
  }
  __syncthreads();
  { int row=tid>>2, c=(tid&3)*16;
    uint4 a=*(const uint4*)&tmp[row*72+c]; uint4 b=*(const uint4*)&tmp[row*72+c+8];
    unsigned short* kr = kk + ((size_t)(h*S_)+s0+row)*128 + 64;
    *(uint4*)&kr[c]=a; *(uint4*)&kr[c+8]=b; }
  stage_B64(Wq_rope + h*4096, Bs, tid);
  __syncthreads();

  #pragma unroll
  for(int nf=0;nf<4;nf++){acc[nf][0]=0.f;acc[nf][1]=0.f;acc[nf][2]=0.f;acc[nf][3]=0.f;}
  gemm64(ckvs, Bs, wv, l16, l4, acc);
  #pragma unroll
  for(int nf=0;nf<4;nf++){
    float bq = bq_rope[h*64 + nf*16+l16];
    #pragma unroll
    for(int r=0;r<4;r++) acc[nf][r]+=bq;
  }
  #pragma unroll
  for(int nf=0;nf<2;nf++){
    int dlo = nf*16+l16;
    float inv = __expf(-(float)dlo * LNC);
    #pragma unroll
    for(int r=0;r<4;r++){
      int srow = wv*16+4*l4+r;
      float sn,cs; __sincosf((float)(s0+srow)*inv,&sn,&cs);
      float alo=acc[nf][r]*ASC, ahi=acc[nf+2][r]*ASC;
      tmp[srow*72 + dlo]      = f2bf(alo*cs - ahi*sn);
      tmp[srow*72 + dlo + 32] = f2bf(ahi*cs + alo*sn);
    }
  }
  __syncthreads();
  { int row=tid>>2, c=(tid&3)*16;
    uint4 a=*(const uint4*)&tmp[row*72+c]; uint4 b=*(const uint4*)&tmp[row*72+c+8];
    unsigned short* qr = qq + ((size_t)(h*S_)+s0+row)*128 + 64;
    *(uint4*)&qr[c]=a; *(uint4*)&qr[c+8]=b; }
  stage_B64(abs_t + h*4096, Bs, tid);
  __syncthreads();

  #pragma unroll
  for(int nf=0;nf<4;nf++){acc[nf][0]=0.f;acc[nf][1]=0.f;acc[nf][2]=0.f;acc[nf][3]=0.f;}
  gemm64(ysd, Bs, wv, l16, l4, acc);
  #pragma unroll
  for(int nf=0;nf<4;nf++)
    #pragma unroll
    for(int r=0;r<4;r++)
      tmp[(wv*16+4*l4+r)*72 + nf*16+l16] = f2bf(acc[nf][r]*ASC);
  __syncthreads();
  { int row=tid>>2, c=(tid&3)*16;
    uint4 a=*(const uint4*)&tmp[row*72+c]; uint4 b=*(const uint4*)&tmp[row*72+c+8];
    unsigned short* qr = qq + ((size_t)(h*S_)+s0+row)*128;
    *(uint4*)&qr[c]=a; *(uint4*)&qr[c+8]=b; }
  stage_B64(wuvt + h*4096, Bs, tid);
  __syncthreads();

  #pragma unroll
  for(int nf=0;nf<4;nf++){acc[nf][0]=0.f;acc[nf][1]=0.f;acc[nf][2]=0.f;acc[nf][3]=0.f;}
  gemm64(ckvs, Bs, wv, l16, l4, acc);
  #pragma unroll
  for(int nf=0;nf<4;nf++)
    #pragma unroll
    for(int r=0;r<4;r++)
      tmp[(wv*16+4*l4+r)*72 + nf*16+l16] = f2bf(acc[nf][r]);
  __syncthreads();
  { int row=tid>>2, c=(tid&3)*16;
    uint4 a=*(const uint4*)&tmp[row*72+c]; uint4 b=*(const uint4*)&tmp[row*72+c+8];
    unsigned short* vr = vv + ((size_t)(h*S_)+s0+row)*64;
    *(uint4*)&vr[c]=a; *(uint4*)&vr[c+8]=b; }
}

// ---------------- MFMA flash attention + Wo + residual ----------------
__global__ __launch_bounds__(256) void k_attn2(const unsigned short* __restrict__ qq,
    const unsigned short* __restrict__ kk, const unsigned short* __restrict__ vv,
    const float* __restrict__ Wo, const float* __restrict__ x, float* __restrict__ x1){
  __shared__ unsigned short Ks[64*128];
  __shared__ unsigned short Vt[64*72];
  __shared__ unsigned short Pl[4][16*72];
  int h = blockIdx.y, q0 = blockIdx.x*64, tid = threadIdx.x;
  int wave = tid>>6, lane = tid&63;
  int l16 = lane&15, l4 = lane>>4;
  int qglob = q0 + wave*16 + l16;

  s16x8 qf[4];
  {
    const unsigned short* qp = qq + ((size_t)(h*S_)+qglob)*128 + l4*8;
    #pragma unroll
    for(int kb=0;kb<4;kb++) qf[kb] = *(const s16x8*)(qp + kb*32);
  }
  fx4 ot[4];
  #pragma unroll
  for(int t=0;t<4;t++){ ot[t][0]=0.f; ot[t][1]=0.f; ot[t][2]=0.f; ot[t][3]=0.f; }
  float mrun=-1e30f, lrun=0.f;
  int nkt = blockIdx.x + 1;

  for(int kt=0;kt<nkt;kt++){
    int kt0 = kt*64;
    __syncthreads();
    #pragma unroll
    for(int it=0;it<4;it++){
      int idx = tid + it*256;
      int row = idx>>4, c = idx&15;
      uint4 u = *(const uint4*)(kk + ((size_t)(h*S_)+kt0+row)*128 + c*8);
      *(uint4*)&Ks[row*128 + ((c^(row&7))<<3)] = u;
    }
    #pragma unroll
    for(int it=0;it<2;it++){
      int idx = tid + it*256;
      int k = idx>>3, d0 = (idx&7)*8;
      uint4 u = *(const uint4*)(vv + ((size_t)(h*S_)+kt0+k)*64 + d0);
      unsigned short t8[8];
      *(uint4*)t8 = u;
      #pragma unroll
      for(int j=0;j<8;j++) Vt[(d0+j)*72 + k] = t8[j];
    }
    __syncthreads();

    fx4 sa[4];
    #pragma unroll
    for(int i=0;i<4;i++){ sa[i][0]=0.f; sa[i][1]=0.f; sa[i][2]=0.f; sa[i][3]=0.f; }
    #pragma unroll
    for(int kb=0;kb<4;kb++){
      #pragma unroll
      for(int i=0;i<4;i++){
        int row = 16*i + l16;
        s16x8 ak = *(const s16x8*)&Ks[row*128 + (((l4+4*kb)^(row&7))<<3)];
        sa[i] = __builtin_amdgcn_mfma_f32_16x16x32_bf16(ak, qf[kb], sa[i], 0,0,0);
      }
    }
    float pv[16]; float mloc=-1e30f;
    #pragma unroll
    for(int i=0;i<4;i++)
      #pragma unroll
      for(int r=0;r<4;r++){
        int kg = kt0 + 16*i + 4*l4 + r;
        float s = (kg<=qglob)? sa[i][r] : -1e30f;
        pv[i*4+r]=s; mloc=fmaxf(mloc,s);
      }
    mloc = fmaxf(mloc, __shfl_xor(mloc,16));
    mloc = fmaxf(mloc, __shfl_xor(mloc,32));
    float mnew = fmaxf(mrun,mloc);
    float alpha = __expf(mrun-mnew);
    float psum=0.f;
    #pragma unroll
    for(int z=0;z<16;z++){ pv[z]=__expf(pv[z]-mnew); psum+=pv[z]; }
    psum += __shfl_xor(psum,16); psum += __shfl_xor(psum,32);
    lrun = lrun*alpha + psum; mrun = mnew;
    #pragma unroll
    for(int t=0;t<4;t++){ ot[t][0]*=alpha; ot[t][1]*=alpha; ot[t][2]*=alpha; ot[t][3]*=alpha; }
    {
      unsigned short* pw = &Pl[wave][l16*72 + 4*l4];
      #pragma unroll
      for(int i=0;i<4;i++){
        *(unsigned int*)&pw[16*i]   = pk2(pv[i*4+0],pv[i*4+1]);
        *(unsigned int*)&pw[16*i+2] = pk2(pv[i*4+2],pv[i*4+3]);
      }
    }
    #pragma unroll
    for(int kb=0;kb<2;kb++){
      s16x8 pf = *(const s16x8*)&Pl[wave][l16*72 + kb*32 + l4*8];
      #pragma unroll
      for(int t=0;t<4;t++){
        s16x8 av = *(const s16x8*)&Vt[(16*t+l16)*72 + kb*32 + l4*8];
        ot[t] = __builtin_amdgcn_mfma_f32_16x16x32_bf16(av, pf, ot[t], 0,0,0);
      }
    }
  }

  float invl = 1.f/lrun;
  {
    unsigned short* pw = &Pl[wave][l16*72 + 4*l4];
    #pragma unroll
    for(int t=0;t<4;t++){
      *(unsigned int*)&pw[16*t]   = pk2(ot[t][0]*invl, ot[t][1]*invl);
      *(unsigned int*)&pw[16*t+2] = pk2(ot[t][2]*invl, ot[t][3]*invl);
    }
  }
  __syncthreads();
  #pragma unroll
  for(int it=0;it<4;it++){
    int idx = tid + it*256;
    int ee = idx>>4, dd = (idx&15)*4;
    float4 wv = *(const float4*)(Wo + h*4096 + ee*64 + dd);
    ushort4 w4; w4.x=f2bf(wv.x); w4.y=f2bf(wv.y); w4.z=f2bf(wv.z); w4.w=f2bf(wv.w);
    *(ushort4*)&Vt[ee*72 + dd] = w4;
  }
  __syncthreads();
  fx4 outT[4];
  #pragma unroll
  for(int t=0;t<4;t++){ outT[t][0]=0.f; outT[t][1]=0.f; outT[t][2]=0.f; outT[t][3]=0.f; }
  #pragma unroll
  for(int kb=0;kb<2;kb++){
    s16x8 of = *(const s16x8*)&Pl[wave][l16*72 + kb*32 + l4*8];
    #pragma unroll
    for(int t=0;t<4;t++){
      s16x8 aw = *(const s16x8*)&Vt[(16*t+l16)*72 + kb*32 + l4*8];
      outT[t] = __builtin_amdgcn_mfma_f32_16x16x32_bf16(aw, of, outT[t], 0,0,0);
    }
  }
  #pragma unroll
  for(int t=0;t<4;t++){
    size_t base = (size_t)qglob*D_ + h*64 + 16*t + 4*l4;
    float4 xv = *(const float4*)(x + base);
    float4 r;
    r.x = xv.x + outT[t][0]; r.y = xv.y + outT[t][1];
    r.z = xv.z + outT[t][2]; r.w = xv.w + outT[t][3];
    *(float4*)(x1+base) = r;
  }
}

// ---------------- gating: rmsnorm (writes y2) + router + noisy top-2 ----------------
__global__ __launch_bounds__(64) void k_gate(const float* __restrict__ x1, const float* __restrict__ Wr,
    const float* __restrict__ Wn, const float* __restrict__ r_bias, const float* __restrict__ noise_u,
    float* __restrict__ gates, int* __restrict__ topi, unsigned short* __restrict__ y2){
  int s = blockIdx.x, lane = threadIdx.x;
  const float* xr = x1 + (size_t)s*D_ + lane*16;
  float yv[16]; float ss=0.f;
  #pragma unroll
  for(int i=0;i<16;i+=4){
    float4 a = *(const float4*)(xr+i);
    yv[i]=a.x; yv[i+1]=a.y; yv[i+2]=a.z; yv[i+3]=a.w;
    ss += a.x*a.x+a.y*a.y+a.z*a.z+a.w*a.w;
  }
  #pragma unroll
  for(int o=1;o<64;o<<=1) ss += __shfl_xor(ss,o);
  float sc = rsqrtf(ss*(1.0f/D_) + 1e-6f);
  #pragma unroll
  for(int i=0;i<16;i++) yv[i]*=sc;
  {
    unsigned short* yo = y2 + (size_t)s*D_ + lane*16;
    ushort4 o0,o1,o2,o3;
    o0.x=f2bf(yv[0]); o0.y=f2bf(yv[1]); o0.z=f2bf(yv[2]); o0.w=f2bf(yv[3]);
    o1.x=f2bf(yv[4]); o1.y=f2bf(yv[5]); o1.z=f2bf(yv[6]); o1.w=f2bf(yv[7]);
    o2.x=f2bf(yv[8]); o2.y=f2bf(yv[9]); o2.z=f2bf(yv[10]); o2.w=f2bf(yv[11]);
    o3.x=f2bf(yv[12]); o3.y=f2bf(yv[13]); o3.z=f2bf(yv[14]); o3.w=f2bf(yv[15]);
    *(ushort4*)(yo)   = o0; *(ushort4*)(yo+4) = o1;
    *(ushort4*)(yo+8) = o2; *(ushort4*)(yo+12)= o3;
  }
  float lg[8], nz[8];
  #pragma unroll
  for(int e=0;e<8;e++){
    const float* wr = Wr + e*D_ + lane*16;
    const float* wn = Wn + e*D_ + lane*16;
    float a=0.f,b=0.f;
    #pragma unroll
    for(int i=0;i<16;i+=4){
      float4 w1 = *(const float4*)(wr+i); float4 w2 = *(const float4*)(wn+i);
      a += yv[i]*w1.x + yv[i+1]*w1.y + yv[i+2]*w1.z + yv[i+3]*w1.w;
      b += yv[i]*w2.x + yv[i+1]*w2.y + yv[i+2]*w2.z + yv[i+3]*w2.w;
    }
    lg[e]=a; nz[e]=b;
  }
  #pragma unroll
  for(int o=1;o<64;o<<=1){
    #pragma unroll
    for(int e=0;e<8;e++){ lg[e]+=__shfl_xor(lg[e],o); nz[e]+=__shfl_xor(nz[e],o); }
  }
  if(lane==0){
    float nl[8];
    for(int e=0;e<8;e++){
      float z = nz[e];
      float sp = (z>20.f)? z : log1pf(expf(z));
      nl[e] = noise_u[s*8+e]*sp + lg[e] + r_bias[e];
    }
    int i0=0; float v0=nl[0];
    for(int e=1;e<8;e++) if(nl[e]>v0){v0=nl[e];i0=e;}
    float v1=-1e30f; int i1=0;
    for(int e=0;e<8;e++) if(e!=i0 && nl[e]>v1){v1=nl[e];i1=e;}
    float ex = expf(v1-v0);
    gates[s*2]   = 1.f/(1.f+ex);
    gates[s*2+1] = ex/(1.f+ex);
    topi[s*2]=i0; topi[s*2+1]=i1;
  }
}

// ---------------- per-expert padded token lists (pad to 256) ----------------
__global__ __launch_bounds__(256) void k_lists(const int* __restrict__ topi,
    int* __restrict__ offs, int* __restrict__ pair_tok, int* __restrict__ slot_of){
  __shared__ int tp[2048];
  __shared__ int cnt[8];
  __shared__ int off_s[9];
  int t = threadIdx.x;
  int wave = t>>6, lane = t&63;
  unsigned long long below = (lane==63)? 0xFFFFFFFFFFFFFFFFull>>1
                                       : ((1ull<<lane)-1ull);
  for(int i=t;i<2048;i+=256) tp[i]=topi[i];
  __syncthreads();
  #pragma unroll
  for(int sub=0;sub<2;sub++){
    int e = wave*2+sub;
    int c=0;
    for(int ch=0;ch<32;ch++) c += (tp[ch*64+lane]==e);
    #pragma unroll
    for(int o=1;o<64;o<<=1) c += __shfl_xor(c,o);
    if(lane==0) cnt[e]=c;
  }
  __syncthreads();
  if(t==0){
    int a=0;
    for(int e=0;e<8;e++){ off_s[e]=a; a += (cnt[e]+255)&~255; }
    off_s[8]=a;
    for(int e=0;e<9;e++) offs[e]=off_s[e];
  }
  __syncthreads();
  #pragma unroll
  for(int sub=0;sub<2;sub++){
    int e = wave*2+sub;
    int base = off_s[e];
    for(int ch=0;ch<32;ch++){
      int idx = ch*64+lane;
      bool pred = (tp[idx]==e);
      unsigned long long mask = __ballot(pred);
      if(pred){
        int slot = base + __popcll(mask & below);
        pair_tok[slot] = idx>>1;
        slot_of[idx] = slot;
      }
      base += __popcll(mask);
    }
    for(int slot=base+lane; slot<off_s[e+1]; slot+=64) pair_tok[slot]=0;
  }
}

// ---------------- transpose-convert: src f32 [e][R][C] -> dst bf16 [e][C][R] ----------------
__global__ __launch_bounds__(256) void k_cvt_t(const float* __restrict__ src,
    unsigned short* __restrict__ dst, int R, int C){
  __shared__ float ts[64][65];
  int e = blockIdx.z;
  int r0 = blockIdx.x*64, c0 = blockIdx.y*64;
  const float* s = src + (size_t)e*R*C;
  unsigned short* d = dst + (size_t)e*R*C;
  int t = threadIdx.x;
  #pragma unroll
  for(int it=0; it<4; it++){
    int flat = it*256+t;
    int r = flat>>4, cq = (flat&15)*4;
    float4 v = *(const float4*)(s + (size_t)(r0+r)*C + c0+cq);
    ts[r][cq]=v.x; ts[r][cq+1]=v.y; ts[r][cq+2]=v.z; ts[r][cq+3]=v.w;
  }
  __syncthreads();
  #pragma unroll
  for(int it=0; it<4; it++){
    int flat = it*256+t;
    int c = flat>>4, kq = (flat&15)*4;
    ushort4 o;
    o.x=f2bf(ts[kq][c]); o.y=f2bf(ts[kq+1][c]); o.z=f2bf(ts[kq+2][c]); o.w=f2bf(ts[kq+3][c]);
    *(ushort4*)(d + (size_t)(c0+c)*R + r0+kq) = o;
  }
}

// ---------------- FC1: 256x256 tile, 8 waves, read-first dbuf pipeline ----------------
__global__ __launch_bounds__(512) void k_fc1t(const unsigned short* __restrict__ y2,
    const int* __restrict__ pair_tok, const int* __restrict__ offs,
    const unsigned short* __restrict__ Bt, const float* __restrict__ bias1,
    unsigned short* __restrict__ hbuf){
  __shared__ unsigned short As[2][16384];   // 2 x 32 KB: [256 rows][64k], granule-swizzled
  __shared__ unsigned short Bs[2][16384];   // 2 x 32 KB
  __shared__ int sh_e;
  int tid=threadIdx.x, lane=tid&63, wv=tid>>6;   // wv 0..7
  int swz = xcd_swz(blockIdx.x, 256);            // grid 16 r x 16 n
  int r0 = (swz & 15)*256, n0 = (swz >> 4)*256;  // consecutive swz share n0 on one XCD
  if(tid==0){ int e=-1; if(r0<offs[8]){e=0; while(offs[e+1]<=r0) e++;} sh_e=e; }
  __syncthreads();
  int e=sh_e; if(e<0) return;
  int rg = lane>>3;
  int sg = (lane&7)^(rg&7);
  const unsigned short* aptr[4];
  const unsigned short* bptr[4];
  #pragma unroll
  for(int c=0;c<4;c++){
    int ch = wv*4+c;                           // 0..31 chunks of 8 rows
    int tok = pair_tok[r0 + ch*8 + rg];
    aptr[c] = y2 + (size_t)tok*D_ + sg*8;
    bptr[c] = Bt + (size_t)e*D_*F_ + (size_t)(n0 + ch*8 + rg)*D_ + sg*8;
  }
  int l16=lane&15, l4=lane>>4;
  int wm=wv>>2, wn=wv&3;                       // 2 x 4 wave grid; wave tile 128M x 64N
  fx4 acc[8][4];
  #pragma unroll
  for(int a0=0;a0<8;a0++)
    #pragma unroll
    for(int b0=0;b0<4;b0++){ acc[a0][b0][0]=0.f; acc[a0][b0][1]=0.f; acc[a0][b0][2]=0.f; acc[a0][b0][3]=0.f; }

  // prologue
  #pragma unroll
  for(int c=0;c<4;c++){
    gld16(aptr[c], &As[0][(wv*4+c)*512]);
    gld16(bptr[c], &Bs[0][(wv*4+c)*512]);
  }

  int buf=0;
  for(int kt=0;kt<D_;kt+=64){
    asm volatile("s_waitcnt vmcnt(0)" ::: "memory");
    asm volatile("s_barrier" ::: "memory");
    // kb=0: read frags, MFMA (register-only)
    {
      s16x8 af[8], bf[4];
      #pragma unroll
      for(int mf=0;mf<8;mf++){
        int row = wm*128+mf*16+l16;
        af[mf] = *(const s16x8*)&As[buf][row*64 + ((l4^(row&7))*8)];
      }
      #pragma unroll
      for(int nf=0;nf<4;nf++){
        int col = wn*64+nf*16+l16;
        bf[nf] = *(const s16x8*)&Bs[buf][col*64 + ((l4^(col&7))*8)];
      }
      __builtin_amdgcn_s_setprio(1);
      #pragma unroll
      for(int mf=0;mf<8;mf++)
        #pragma unroll
        for(int nf=0;nf<4;nf++)
          acc[mf][nf]=__builtin_amdgcn_mfma_f32_16x16x32_bf16(af[mf],bf[nf],acc[mf][nf],0,0,0);
      __builtin_amdgcn_s_setprio(0);
    }
    // kb=1: read frags, then issue next-tile loads, then MFMA
    {
      s16x8 af[8], bf[4];
      #pragma unroll
      for(int mf=0;mf<8;mf++){
        int row = wm*128+mf*16+l16;
        af[mf] = *(const s16x8*)&As[buf][row*64 + (((4+l4)^(row&7))*8)];
      }
      #pragma unroll
      for(int nf=0;nf<4;nf++){
        int col = wn*64+nf*16+l16;
        bf[nf] = *(const s16x8*)&Bs[buf][col*64 + (((4+l4)^(col&7))*8)];
      }
      if(kt+64<D_){
        #pragma unroll
        for(int c=0;c<4;c++){
          gld16(aptr[c]+kt+64, &As[buf^1][(wv*4+c)*512]);
          gld16(bptr[c]+kt+64, &Bs[buf^1][(wv*4+c)*512]);
        }
      }
      __builtin_amdgcn_sched_barrier(0);
      __builtin_amdgcn_s_setprio(1);
      #pragma unroll
      for(int mf=0;mf<8;mf++)
        #pragma unroll
        for(int nf=0;nf<4;nf++)
          acc[mf][nf]=__builtin_amdgcn_mfma_f32_16x16x32_bf16(af[mf],bf[nf],acc[mf][nf],0,0,0);
      __builtin_amdgcn_s_setprio(0);
    }
    asm volatile("s_barrier" ::: "memory");
    buf ^= 1;
  }
  #pragma unroll
  for(int mf=0;mf<8;mf++)
    #pragma unroll
    for(int nf=0;nf<4;nf++){
      int gcol=n0+wn*64+nf*16+l16;
      float bias=bias1[e*F_+gcol];
      #pragma unroll
      for(int rgi=0;rgi<4;rgi++){
        int grow=r0+wm*128+mf*16+l4*4+rgi;
        float vv=acc[mf][nf][rgi]+bias;
        float g=0.5f*vv*(1.f+erff(vv*0.70710678118654752f));
        hbuf[(size_t)grow*F_+gcol]=f2bf(g);
      }
    }
}

// ---------------- FC2: read-frags-first pipeline, split-K (4096-row space) ----------------
__global__ __launch_bounds__(256) void k_fc2t(const unsigned short* __restrict__ hbuf,
    const int* __restrict__ offs, const unsigned short* __restrict__ Bt,
    const float* __restrict__ bias2, float* __restrict__ eo, int klen, int parts){
  __shared__ unsigned short As[2][8192];
  __shared__ unsigned short Bs[2][4096];
  __shared__ int sh_e;
  int tid=threadIdx.x, lane=tid&63, wv=tid>>6;
  int nwg = 512*parts;
  int swz = xcd_swz(blockIdx.x, nwg);
  int kz  = swz / 512;
  int rem = swz % 512;
  int r0 = (rem & 31)*128, n0 = (rem >> 5)*64;
  int k0 = kz*klen;
  if(tid==0){ int e=-1; if(r0<offs[8]){e=0; while(offs[e+1]<=r0) e++;} sh_e=e; }
  __syncthreads();
  int e=sh_e; if(e<0) return;
  int rg = lane>>3;
  int sg = (lane&7)^(rg&7);
  const unsigned short* aptr[4];
  const unsigned short* bptr[2];
  #pragma unroll
  for(int c=0;c<4;c++){
    int ch = wv*4+c;
    aptr[c] = hbuf + (size_t)(r0 + ch*8 + rg)*F_ + k0 + sg*8;
  }
  #pragma unroll
  for(int c=0;c<2;c++){
    int ch = wv*2+c;
    bptr[c] = Bt + (size_t)e*F_*D_ + (size_t)(n0 + ch*8 + rg)*F_ + k0 + sg*8;
  }
  int l16=lane&15, l4=lane>>4;
  fx4 acc[2][4];
  #pragma unroll
  for(int a0=0;a0<2;a0++)
    #pragma unroll
    for(int b0=0;b0<4;b0++){ acc[a0][b0][0]=0.f; acc[a0][b0][1]=0.f; acc[a0][b0][2]=0.f; acc[a0][b0][3]=0.f; }

  #pragma unroll
  for(int c=0;c<4;c++) gld16(aptr[c], &As[0][(wv*4+c)*512]);
  #pragma unroll
  for(int c=0;c<2;c++) gld16(bptr[c], &Bs[0][(wv*2+c)*512]);

  int buf=0;
  for(int kt=0;kt<klen;kt+=64){
    asm volatile("s_waitcnt vmcnt(0)" ::: "memory");
    asm volatile("s_barrier" ::: "memory");
    s16x8 af[2][2], bf[2][4];
    #pragma unroll
    for(int kb=0;kb<2;kb++){
      #pragma unroll
      for(int mf=0;mf<2;mf++){
        int row = wv*32+mf*16+l16;
        af[kb][mf] = *(const s16x8*)&As[buf][row*64 + (((kb*4+l4)^(row&7))*8)];
      }
      #pragma unroll
      for(int nf=0;nf<4;nf++){
        int col = nf*16+l16;
        bf[kb][nf] = *(const s16x8*)&Bs[buf][col*64 + (((kb*4+l4)^(col&7))*8)];
      }
    }
    if(kt+64<klen){
      #pragma unroll
      for(int c=0;c<4;c++) gld16(aptr[c]+kt+64, &As[buf^1][(wv*4+c)*512]);
      #pragma unroll
      for(int c=0;c<2;c++) gld16(bptr[c]+kt+64, &Bs[buf^1][(wv*2+c)*512]);
    }
    __builtin_amdgcn_sched_barrier(0);
    __builtin_amdgcn_s_setprio(1);
    #pragma unroll
    for(int kb=0;kb<2;kb++)
      #pragma unroll
      for(int mf=0;mf<2;mf++)
        #pragma unroll
        for(int nf=0;nf<4;nf++)
          acc[mf][nf]=__builtin_amdgcn_mfma_f32_16x16x32_bf16(af[kb][mf],bf[kb][nf],acc[mf][nf],0,0,0);
    __builtin_amdgcn_s_setprio(0);
    asm volatile("s_barrier" ::: "memory");
    buf ^= 1;
  }
  float* eop = eo + (size_t)kz*4096*D_;
  #pragma unroll
  for(int mf=0;mf<2;mf++)
    #pragma unroll
    for(int nf=0;nf<4;nf++){
      int gcol=n0+nf*16+l16;
      float bias=(kz==0)? bias2[e*D_+gcol] : 0.f;
      #pragma unroll
      for(int rgi=0;rgi<4;rgi++){
        int grow=r0+wv*32+mf*16+l4*4+rgi;
        eop[(size_t)grow*D_+gcol]=acc[mf][nf][rgi]+bias;
      }
    }
}

// ---------------- fallback FC kernels (round-6 proven) ----------------
__global__ __launch_bounds__(256) void k_fc1_fb(const unsigned short* __restrict__ y2,
    const int* __restrict__ pair_tok, const int* __restrict__ offs,
    const float* __restrict__ W1, const float* __restrict__ bias1,
    unsigned short* __restrict__ hbuf){
  __shared__ unsigned short As[4096];
  __shared__ unsigned short Bs[4096];
  __shared__ int sh_e;
  int tid=threadIdx.x;
  int r0=blockIdx.x*128, n0=blockIdx.y*128;
  if(tid==0){ int e=-1; if(r0<offs[8]){ e=0; while(offs[e+1]<=r0) e++; } sh_e=e; }
  __syncthreads();
  int e=sh_e; if(e<0) return;
  const float* Bsrc = W1 + (size_t)e*D_*F_;
  int r=tid&127, hf=tid>>7;
  int tok=pair_tok[r0+r];
  const unsigned short* Asrc = y2 + (size_t)tok*D_ + hf*16;
  int pk=tid>>5, pn=tid&31;
  int lane=tid&63, wvid=tid>>6;
  int wm=wvid>>1, wn=wvid&1;
  int l16=lane&15, l4=lane>>4;
  fx4 acc[4][4];
  #pragma unroll
  for(int a0=0;a0<4;a0++)
    #pragma unroll
    for(int b0=0;b0<4;b0++){ acc[a0][b0][0]=0.f; acc[a0][b0][1]=0.f; acc[a0][b0][2]=0.f; acc[a0][b0][3]=0.f; }
  for(int kt=0;kt<D_;kt+=32){
    uint4 av0=*(const uint4*)(Asrc+kt);
    uint4 av1=*(const uint4*)(Asrc+kt+8);
    const float* bp=Bsrc+(size_t)(kt+pk*4)*F_+n0+pn*4;
    float4 bv0=*(const float4*)(bp);
    float4 bv1=*(const float4*)(bp+F_);
    float4 bv2=*(const float4*)(bp+2*F_);
    float4 bv3=*(const float4*)(bp+3*F_);
    *(uint4*)&As[(hf*2)*1024 + r*8]=av0;
    *(uint4*)&As[(hf*2+1)*1024 + r*8]=av1;
    unsigned short c0[4]={f2bf(bv0.x),f2bf(bv0.y),f2bf(bv0.z),f2bf(bv0.w)};
    unsigned short c1[4]={f2bf(bv1.x),f2bf(bv1.y),f2bf(bv1.z),f2bf(bv1.w)};
    unsigned short c2[4]={f2bf(bv2.x),f2bf(bv2.y),f2bf(bv2.z),f2bf(bv2.w)};
    unsigned short c3[4]={f2bf(bv3.x),f2bf(bv3.y),f2bf(bv3.z),f2bf(bv3.w)};
    #pragma unroll
    for(int j2=0;j2<4;j2++){
      int col=pn*4+j2;
      int kb=(pk*4)^(((col>>2)&3)<<3);
      ushort4 wr;
      wr.x=c0[j2]; wr.y=c1[j2]; wr.z=c2[j2]; wr.w=c3[j2];
      *(ushort4*)&Bs[col*32+kb]=wr;
    }
    __syncthreads();
    s16x8 af[4],bf8[4];
    #pragma unroll
    for(int mf=0;mf<4;mf++){
      int rowl=wm*64+mf*16+l16;
      af[mf]=*(const s16x8*)&As[l4*1024+rowl*8];
    }
    #pragma unroll
    for(int nf=0;nf<4;nf++){
      int col=wn*64+nf*16+l16;
      int kb=(l4*8)^(((col>>2)&3)<<3);
      bf8[nf]=*(const s16x8*)&Bs[col*32+kb];
    }
    #pragma unroll
    for(int mf=0;mf<4;mf++)
      #pragma unroll
      for(int nf=0;nf<4;nf++)
        acc[mf][nf]=__builtin_amdgcn_mfma_f32_16x16x32_bf16(af[mf],bf8[nf],acc[mf][nf],0,0,0);
    __syncthreads();
  }
  #pragma unroll
  for(int mf=0;mf<4;mf++)
    #pragma unroll
    for(int nf=0;nf<4;nf++){
      int gcol=n0+wn*64+nf*16+l16;
      float bias=bias1[e*F_+gcol];
      #pragma unroll
      for(int rg=0;rg<4;rg++){
        int grow=r0+wm*64+mf*16+l4*4+rg;
        float vv=acc[mf][nf][rg]+bias;
        float g=0.5f*vv*(1.f+erff(vv*0.70710678118654752f));
        hbuf[(size_t)grow*F_+gcol]=f2bf(g);
      }
    }
}

__global__ __launch_bounds__(256) void k_fc2_fb(const unsigned short* __restrict__ hbuf,
    const int* __restrict__ offs, const float* __restrict__ W2,
    const float* __restrict__ bias2, float* __restrict__ eo){
  __shared__ unsigned short As[4096];
  __shared__ unsigned short Bs[2048];
  __shared__ int sh_e;
  int tid=threadIdx.x;
  int r0=blockIdx.x*128, n0=blockIdx.y*64;
  if(tid==0){ int e=-1; if(r0<offs[8]){ e=0; while(offs[e+1]<=r0) e++; } sh_e=e; }
  __syncthreads();
  int e=sh_e; if(e<0) return;
  const float* Bsrc=W2+(size_t)e*F_*D_;
  int r=tid&127, hf=tid>>7;
  const unsigned short* Asrc=hbuf+(size_t)(r0+r)*F_+hf*16;
  int pk=tid>>4, pn=tid&15;
  int lane=tid&63, wvid=tid>>6;
  int l16=lane&15, l4=lane>>4;
  fx4 acc[2][4];
  #pragma unroll
  for(int a0=0;a0<2;a0++)
    #pragma unroll
    for(int b0=0;b0<4;b0++){ acc[a0][b0][0]=0.f; acc[a0][b0][1]=0.f; acc[a0][b0][2]=0.f; acc[a0][b0][3]=0.f; }
  for(int kt=0;kt<F_;kt+=32){
    uint4 av0=*(const uint4*)(Asrc+kt);
    uint4 av1=*(const uint4*)(Asrc+kt+8);
    const float* bp=Bsrc+(size_t)(kt+pk*2)*D_+n0+pn*4;
    float4 bv0=*(const float4*)bp;
    float4 bv1=*(const float4*)(bp+D_);
    *(uint4*)&As[(hf*2)*1024+r*8]=av0;
    *(uint4*)&As[(hf*2+1)*1024+r*8]=av1;
    unsigned short c0[4]={f2bf(bv0.x),f2bf(bv0.y),f2bf(bv0.z),f2bf(bv0.w)};
    unsigned short c1[4]={f2bf(bv1.x),f2bf(bv1.y),f2bf(bv1.z),f2bf(bv1.w)};
    #pragma unroll
    for(int j2=0;j2<4;j2++){
      int col=pn*4+j2;
      int kb=(pk*2)^(((col>>2)&3)<<3);
      unsigned int pack=(unsigned int)c0[j2] | ((unsigned int)c1[j2]<<16);
      *(unsigned int*)&Bs[col*32+kb]=pack;
    }
    __syncthreads();
    s16x8 af[2],bf8[4];
    #pragma unroll
    for(int mf=0;mf<2;mf++){
      int rowl=wvid*32+mf*16+l16;
      af[mf]=*(const s16x8*)&As[l4*1024+rowl*8];
    }
    #pragma unroll
    for(int nf=0;nf<4;nf++){
      int col=nf*16+l16;
      int kb=(l4*8)^(((col>>2)&3)<<3);
      bf8[nf]=*(const s16x8*)&Bs[col*32+kb];
    }
    #pragma unroll
    for(int mf=0;mf<2;mf++)
      #pragma unroll
      for(int nf=0;nf<4;nf++)
        acc[mf][nf]=__builtin_amdgcn_mfma_f32_16x16x32_bf16(af[mf],bf8[nf],acc[mf][nf],0,0,0);
    __syncthreads();
  }
  #pragma unroll
  for(int mf=0;mf<2;mf++)
    #pragma unroll
    for(int nf=0;nf<4;nf++){
      int gcol=n0+nf*16+l16;
      float bias=bias2[e*D_+gcol];
      #pragma unroll
      for(int rg=0;rg<4;rg++){
        int grow=r0+wvid*32+mf*16+l4*4+rg;
        eo[(size_t)grow*D_+gcol]=acc[mf][nf][rg]+bias;
      }
    }
}

// ---------------- combine ----------------
__global__ __launch_bounds__(256) void k_combine(const float* __restrict__ x1, const float* __restrict__ eo,
    int parts, const float* __restrict__ gates, const int* __restrict__ slot_of, float* __restrict__ out){
  int s=blockIdx.x, t=threadIdx.x;
  float g0=gates[s*2], g1=gates[s*2+1];
  int a0=slot_of[s*2], a1=slot_of[s*2+1];
  float4 o=((const float4*)(x1+(size_t)s*D_))[t];
  for(int p=0;p<parts;p++){
    const float* ep = eo + (size_t)p*4096*D_;
    float4 e0=((const float4*)(ep+(size_t)a0*D_))[t];
    float4 e1=((const float4*)(ep+(size_t)a1*D_))[t];
    o.x+=g0*e0.x+g1*e1.x;
    o.y+=g0*e0.y+g1*e1.y;
    o.z+=g0*e0.z+g1*e1.z;
    o.w+=g0*e0.w+g1*e1.w;
  }
  ((float4*)(out+(size_t)s*D_))[t]=o;
}

extern "C" void kernel_launch(void* const* d_in, const int* in_sizes, int n_in,
                              void* d_out, int out_size, void* d_ws, size_t ws_size,
                              hipStream_t stream){
  (void)in_sizes; (void)n_in; (void)out_size;
  const float* x       = (const float*)d_in[0];
  const float* noise_u = (const float*)d_in[1];
  const float* Wdkv    = (const float*)d_in[2];
  const float* Wq      = (const float*)d_in[3];
  const float* Wuv     = (const float*)d_in[4];
  const float* Wuk     = (const float*)d_in[5];
  const float* Wk_rope = (const float*)d_in[6];
  const float* Wq_rope = (const float*)d_in[7];
  const float* bq_rope = (const float*)d_in[8];
  const float* Wo_head = (const float*)d_in[9];
  const float* Wr      = (const float*)d_in[10];
  const float* Wn      = (const float*)d_in[11];
  const float* r_bias  = (const float*)d_in[12];
  const float* W1      = (const float*)d_in[13];
  const float* b1      = (const float*)d_in[14];
  const float* W2      = (const float*)d_in[15];
  const float* b2      = (const float*)d_in[16];
  float* out           = (float*)d_out;

  char* w = (char*)d_ws;
  unsigned short* y    = (unsigned short*)(w);             // 2 MB
  unsigned short* kk   = (unsigned short*)(w + 2097152);   // 4 MB
  unsigned short* qq   = (unsigned short*)(w + 6291456);   // 4 MB
  unsigned short* vv   = (unsigned short*)(w + 10485760);  // 2 MB
  float* abs_t         = (float*)(w + 12582912);           // 256 KB
  float* wuvt          = (float*)(w + 12845056);           // 256 KB
  float* x1            = (float*)(w + 13107200);           // 4 MB
  unsigned short* y2   = (unsigned short*)(w + 17301504);  // 2 MB
  float* gates         = (float*)(w + 19398656);           // 8 KB
  int* topi            = (int*)(w + 19406848);             // 8 KB
  int* slot_of         = (int*)(w + 19415040);             // 8 KB
  int* offs            = (int*)(w + 19423232);             // 4 KB
  int* pair_tok        = (int*)(w + 19427328);             // 16 KB
  unsigned short* hbuf = (unsigned short*)(w + 19443712);  // 4096 x 4096 bf16 = 32 MB -> ends 52998144
  float* eo            = (float*)(w + 52998144);           // up to 4 x 16 MB (4096 x 1024 f32 each)

  const size_t NEED4 = 187215872ull;   // eo x4 (ends 120107008) + Wt 64 MB
  const size_t NEED2 = 153661440ull;   // eo x2 (ends  86552576) + Wt 64 MB
  int parts; unsigned short* Wt;
  if(ws_size >= NEED4){ parts = 4; Wt = (unsigned short*)(w + 120107008); }
  else if(ws_size >= NEED2){ parts = 2; Wt = (unsigned short*)(w + 86552576); }
  else { parts = 0; Wt = 0; }

  if(parts){
    k_cvt_t<<<dim3(16,64,8),256,0,stream>>>(W1, Wt, D_, F_);   // W1t [e][n=F][k=D]
  }
  k_rmsnorm<<<S_,256,0,stream>>>(x, y);
  k_prep<<<H_,256,0,stream>>>(Wq, Wuk, Wuv, abs_t, wuvt);
  k_proj_m<<<dim3(16,H_),256,0,stream>>>(y, abs_t, wuvt, Wdkv, Wk_rope, Wq_rope, bq_rope, kk, qq, vv);
  k_attn2<<<dim3(16,H_),256,0,stream>>>(qq, kk, vv, Wo_head, x, x1);
  k_gate<<<S_,64,0,stream>>>(x1, Wr, Wn, r_bias, noise_u, gates, topi, y2);
  k_lists<<<1,256,0,stream>>>(topi, offs, pair_tok, slot_of);
  if(parts){
    k_fc1t<<<256,512,0,stream>>>(y2, pair_tok, offs, Wt, b1, hbuf);
    k_cvt_t<<<dim3(64,16,8),256,0,stream>>>(W2, Wt, F_, D_);   // W2t [e][n=D][k=F]
    k_fc2t<<<512*parts,256,0,stream>>>(hbuf, offs, Wt, b2, eo, F_/parts, parts);
    k_combine<<<S_,256,0,stream>>>(x1, eo, parts, gates, slot_of, out);
  } else {
    k_fc1_fb<<<dim3(32,32),256,0,stream>>>(y2, pair_tok, offs, W1, b1, hbuf);
    k_fc2_fb<<<dim3(32,16),256,0,stream>>>(hbuf, offs, W2, b2, eo);
    k_combine<<<S_,256,0,stream>>>(x1, eo, 1, gates, slot_of, out);
  }
}

// Round 16
// 288.628 us; speedup vs baseline: 1.3882x; 1.3882x over previous
//
#include <hip/hip_runtime.h>
#include <math.h>

#define S_ 1024
#define D_ 1024
#define H_ 16
#define F_ 4096

typedef short s16x8 __attribute__((ext_vector_type(8)));
typedef float fx4 __attribute__((ext_vector_type(4)));

__device__ __forceinline__ float bf2f(unsigned int u){
  union { float f; unsigned int u; } v; v.u = u<<16; return v.f;
}
__device__ __forceinline__ unsigned short f2bf(float f){
  union { float f; unsigned int u; } v; v.f = f;
  unsigned int r = v.u + 0x7fffu + ((v.u>>16)&1u);
  return (unsigned short)(r>>16);
}
__device__ __forceinline__ unsigned int pk2(float a, float b){
  return (unsigned int)f2bf(a) | ((unsigned int)f2bf(b)<<16);
}
__device__ __forceinline__ void gld16(const void* g, void* l){
  typedef const unsigned int __attribute__((address_space(1)))* gp_t;
  typedef unsigned int __attribute__((address_space(3)))* lp_t;
  __builtin_amdgcn_global_load_lds((gp_t)g, (lp_t)l, 16, 0, 0);
}
__device__ __forceinline__ int xcd_swz(int bid, int nwg){
  int q = nwg >> 3;
  return (bid & 7)*q + (bid >> 3);
}

// ---------------- rmsnorm: f32 [S,D] -> bf16 [S,D] ----------------
__global__ __launch_bounds__(256) void k_rmsnorm(const float* __restrict__ x, unsigned short* __restrict__ y){
  int row = blockIdx.x, t = threadIdx.x;
  const float4 v = ((const float4*)(x + (size_t)row*D_))[t];
  float ss = v.x*v.x + v.y*v.y + v.z*v.z + v.w*v.w;
  #pragma unroll
  for(int o=1;o<64;o<<=1) ss += __shfl_xor(ss, o);
  __shared__ float red[4];
  if((t&63)==0) red[t>>6]=ss;
  __syncthreads();
  float sc = rsqrtf((red[0]+red[1]+red[2]+red[3])*(1.0f/D_) + 1e-6f);
  ushort4 o4;
  o4.x=f2bf(v.x*sc); o4.y=f2bf(v.y*sc); o4.z=f2bf(v.z*sc); o4.w=f2bf(v.w*sc);
  ((ushort4*)(y + (size_t)row*D_))[t]=o4;
}

// ---------------- prep: abs_t[h][l][d]; wuvt[h][d][l] ----------------
__global__ __launch_bounds__(256) void k_prep(const float* __restrict__ Wq,
    const float* __restrict__ Wuk, const float* __restrict__ Wuv,
    float* __restrict__ abs_t, float* __restrict__ wuvt){
  int h = blockIdx.x, tid = threadIdx.x;
  __shared__ float wq[4096], wuk[4096];
  for(int i=tid;i<4096;i+=256){ wq[i]=Wq[h*4096+i]; wuk[i]=Wuk[h*4096+i]; }
  __syncthreads();
  for(int i=tid;i<4096;i+=256){
    float a=0.f;
    #pragma unroll 8
    for(int e=0;e<64;e++) a += wq[(i&63)*64+e]*wuk[(i>>6)*64+e];
    abs_t[h*4096+i]=a;
    wuvt[h*4096+i]=Wuv[h*4096 + (i&63)*64 + (i>>6)];
  }
}

// ---------------- MFMA projection helpers ----------------
__device__ __forceinline__ void stage_B64(const float* __restrict__ W, unsigned short* Bs, int tid){
  int n = tid>>2, kq = tid&3;
  const float* s = W + n*64 + kq*16;
  float4 f0=*(const float4*)(s), f1=*(const float4*)(s+4), f2=*(const float4*)(s+8), f3=*(const float4*)(s+12);
  ushort4 u0,u1,u2,u3;
  u0.x=f2bf(f0.x);u0.y=f2bf(f0.y);u0.z=f2bf(f0.z);u0.w=f2bf(f0.w);
  u1.x=f2bf(f1.x);u1.y=f2bf(f1.y);u1.z=f2bf(f1.z);u1.w=f2bf(f1.w);
  u2.x=f2bf(f2.x);u2.y=f2bf(f2.y);u2.z=f2bf(f2.z);u2.w=f2bf(f2.w);
  u3.x=f2bf(f3.x);u3.y=f2bf(f3.y);u3.z=f2bf(f3.z);u3.w=f2bf(f3.w);
  int sl0=((kq*2)^(n&7))*8, sl1=((kq*2+1)^(n&7))*8;
  *(ushort4*)&Bs[n*64+sl0]=u0;   *(ushort4*)&Bs[n*64+sl0+4]=u1;
  *(ushort4*)&Bs[n*64+sl1]=u2;   *(ushort4*)&Bs[n*64+sl1+4]=u3;
}
__device__ __forceinline__ void gemm64(const unsigned short* Asrc, const unsigned short* Bs,
    int wv, int l16, int l4, fx4 acc[4]){
  int srow = wv*16 + l16;
  #pragma unroll
  for(int kb=0;kb<2;kb++){
    s16x8 af = *(const s16x8*)&Asrc[srow*64 + (((kb*4+l4)^(srow&7))*8)];
    #pragma unroll
    for(int nf=0;nf<4;nf++){
      int n = nf*16+l16;
      s16x8 bf = *(const s16x8*)&Bs[n*64 + (((kb*4+l4)^(n&7))*8)];
      acc[nf] = __builtin_amdgcn_mfma_f32_16x16x32_bf16(af, bf, acc[nf], 0,0,0);
    }
  }
}

// ---------------- per-head projections via MFMA ----------------
__global__ __launch_bounds__(256) void k_proj_m(const unsigned short* __restrict__ y,
    const float* __restrict__ abs_t, const float* __restrict__ wuvt,
    const float* __restrict__ Wdkv, const float* __restrict__ Wk_rope,
    const float* __restrict__ Wq_rope, const float* __restrict__ bq_rope,
    unsigned short* __restrict__ kk, unsigned short* __restrict__ qq,
    unsigned short* __restrict__ vv){
  __shared__ unsigned short ysd[4096];
  __shared__ unsigned short ckvs[4096];
  __shared__ unsigned short Bs[4096];
  __shared__ unsigned short tmp[64*72];
  const float LNC = 0.28782313662425575f;
  const float ASC = 0.08838834764831845f;
  int s0 = blockIdx.x*64, h = blockIdx.y, tid = threadIdx.x;
  int wv = tid>>6, lane = tid&63, l16 = lane&15, l4 = lane>>4;
  fx4 acc[4];

  {
    int rg = lane>>3, sg = (lane&7)^(rg&7);
    #pragma unroll
    for(int c2=0;c2<2;c2++){
      int c = wv*2+c2;
      gld16(y + (size_t)(s0+c*8+rg)*D_ + h*64 + sg*8, &ysd[c*512]);
    }
  }
  stage_B64(Wdkv + h*4096, Bs, tid);
  __syncthreads();

  #pragma unroll
  for(int nf=0;nf<4;nf++){acc[nf][0]=0.f;acc[nf][1]=0.f;acc[nf][2]=0.f;acc[nf][3]=0.f;}
  gemm64(ysd, Bs, wv, l16, l4, acc);
  #pragma unroll
  for(int nf=0;nf<4;nf++){
    int col = nf*16+l16;
    #pragma unroll
    for(int r=0;r<4;r++){
      int srow = wv*16+4*l4+r;
      ckvs[srow*64 + (((col>>3)^(srow&7))*8) + (col&7)] = f2bf(acc[nf][r]);
    }
  }
  __syncthreads();
  { int row=tid>>2, sl=(tid&3)*2;
    uint4 a=*(const uint4*)&ckvs[row*64+sl*8];
    uint4 b=*(const uint4*)&ckvs[row*64+sl*8+8];
    unsigned short* kr = kk + ((size_t)(h*S_)+s0+row)*128;
    *(uint4*)&kr[(sl^(row&7))*8]=a;
    *(uint4*)&kr[((sl+1)^(row&7))*8]=b;
  }
  stage_B64(Wk_rope + h*4096, Bs, tid);
  __syncthreads();

  #pragma unroll
  for(int nf=0;nf<4;nf++){acc[nf][0]=0.f;acc[nf][1]=0.f;acc[nf][2]=0.f;acc[nf][3]=0.f;}
  gemm64(ysd, Bs, wv, l16, l4, acc);
  #pragma unroll
  for(int nf=0;nf<2;nf++){
    int llo = nf*16+l16;
    float inv = __expf(-(float)llo * LNC);
    #pragma unroll
    for(int r=0;r<4;r++){
      int srow = wv*16+4*l4+r;
      float sn,cs; __sincosf((float)(s0+srow)*inv,&sn,&cs);
      float alo=acc[nf][r], ahi=acc[nf+2][r];
      tmp[srow*72 + llo]      = f2bf(alo*cs - ahi*sn);
      tmp[srow*72 + llo + 32] = f2bf(ahi*cs + alo*sn);
    }
  }
  __syncthreads();
  { int row=tid>>2, c=(tid&3)*16;
    uint4 a=*(const uint4*)&tmp[row*72+c]; uint4 b=*(const uint4*)&tmp[row*72+c+8];
    unsigned short* kr = kk + ((size_t)(h*S_)+s0+row)*128 + 64;
    *(uint4*)&kr[c]=a; *(uint4*)&kr[c+8]=b; }
  stage_B64(Wq_rope + h*4096, Bs, tid);
  __syncthreads();

  #pragma unroll
  for(int nf=0;nf<4;nf++){acc[nf][0]=0.f;acc[nf][1]=0.f;acc[nf][2]=0.f;acc[nf][3]=0.f;}
  gemm64(ckvs, Bs, wv, l16, l4, acc);
  #pragma unroll
  for(int nf=0;nf<4;nf++){
    float bq = bq_rope[h*64 + nf*16+l16];
    #pragma unroll
    for(int r=0;r<4;r++) acc[nf][r]+=bq;
  }
  #pragma unroll
  for(int nf=0;nf<2;nf++){
    int dlo = nf*16+l16;
    float inv = __expf(-(float)dlo * LNC);
    #pragma unroll
    for(int r=0;r<4;r++){
      int srow = wv*16+4*l4+r;
      float sn,cs; __sincosf((float)(s0+srow)*inv,&sn,&cs);
      float alo=acc[nf][r]*ASC, ahi=acc[nf+2][r]*ASC;
      tmp[srow*72 + dlo]      = f2bf(alo*cs - ahi*sn);
      tmp[srow*72 + dlo + 32] = f2bf(ahi*cs + alo*sn);
    }
  }
  __syncthreads();
  { int row=tid>>2, c=(tid&3)*16;
    uint4 a=*(const uint4*)&tmp[row*72+c]; uint4 b=*(const uint4*)&tmp[row*72+c+8];
    unsigned short* qr = qq + ((size_t)(h*S_)+s0+row)*128 + 64;
    *(uint4*)&qr[c]=a; *(uint4*)&qr[c+8]=b; }
  stage_B64(abs_t + h*4096, Bs, tid);
  __syncthreads();

  #pragma unroll
  for(int nf=0;nf<4;nf++){acc[nf][0]=0.f;acc[nf][1]=0.f;acc[nf][2]=0.f;acc[nf][3]=0.f;}
  gemm64(ysd, Bs, wv, l16, l4, acc);
  #pragma unroll
  for(int nf=0;nf<4;nf++)
    #pragma unroll
    for(int r=0;r<4;r++)
      tmp[(wv*16+4*l4+r)*72 + nf*16+l16] = f2bf(acc[nf][r]*ASC);
  __syncthreads();
  { int row=tid>>2, c=(tid&3)*16;
    uint4 a=*(const uint4*)&tmp[row*72+c]; uint4 b=*(const uint4*)&tmp[row*72+c+8];
    unsigned short* qr = qq + ((size_t)(h*S_)+s0+row)*128;
    *(uint4*)&qr[c]=a; *(uint4*)&qr[c+8]=b; }
  stage_B64(wuvt + h*4096, Bs, tid);
  __syncthreads();

  #pragma unroll
  for(int nf=0;nf<4;nf++){acc[nf][0]=0.f;acc[nf][1]=0.f;acc[nf][2]=0.f;acc[nf][3]=0.f;}
  gemm64(ckvs, Bs, wv, l16, l4, acc);
  #pragma unroll
  for(int nf=0;nf<4;nf++)
    #pragma unroll
    for(int r=0;r<4;r++)
      tmp[(wv*16+4*l4+r)*72 + nf*16+l16] = f2bf(acc[nf][r]);
  __syncthreads();
  { int row=tid>>2, c=(tid&3)*16;
    uint4 a=*(const uint4*)&tmp[row*72+c]; uint4 b=*(const uint4*)&tmp[row*72+c+8];
    unsigned short* vr = vv + ((size_t)(h*S_)+s0+row)*64;
    *(uint4*)&vr[c]=a; *(uint4*)&vr[c+8]=b; }
}

// ---------------- MFMA flash attention + Wo + residual ----------------
__global__ __launch_bounds__(256) void k_attn2(const unsigned short* __restrict__ qq,
    const unsigned short* __restrict__ kk, const unsigned short* __restrict__ vv,
    const float* __restrict__ Wo, const float* __restrict__ x, float* __restrict__ x1){
  __shared__ unsigned short Ks[64*128];
  __shared__ unsigned short Vt[64*72];
  __shared__ unsigned short Pl[4][16*72];
  int h = blockIdx.y, q0 = blockIdx.x*64, tid = threadIdx.x;
  int wave = tid>>6, lane = tid&63;
  int l16 = lane&15, l4 = lane>>4;
  int qglob = q0 + wave*16 + l16;

  s16x8 qf[4];
  {
    const unsigned short* qp = qq + ((size_t)(h*S_)+qglob)*128 + l4*8;
    #pragma unroll
    for(int kb=0;kb<4;kb++) qf[kb] = *(const s16x8*)(qp + kb*32);
  }
  fx4 ot[4];
  #pragma unroll
  for(int t=0;t<4;t++){ ot[t][0]=0.f; ot[t][1]=0.f; ot[t][2]=0.f; ot[t][3]=0.f; }
  float mrun=-1e30f, lrun=0.f;
  int nkt = blockIdx.x + 1;

  for(int kt=0;kt<nkt;kt++){
    int kt0 = kt*64;
    __syncthreads();
    #pragma unroll
    for(int it=0;it<4;it++){
      int idx = tid + it*256;
      int row = idx>>4, c = idx&15;
      uint4 u = *(const uint4*)(kk + ((size_t)(h*S_)+kt0+row)*128 + c*8);
      *(uint4*)&Ks[row*128 + ((c^(row&7))<<3)] = u;
    }
    #pragma unroll
    for(int it=0;it<2;it++){
      int idx = tid + it*256;
      int k = idx>>3, d0 = (idx&7)*8;
      uint4 u = *(const uint4*)(vv + ((size_t)(h*S_)+kt0+k)*64 + d0);
      unsigned short t8[8];
      *(uint4*)t8 = u;
      #pragma unroll
      for(int j=0;j<8;j++) Vt[(d0+j)*72 + k] = t8[j];
    }
    __syncthreads();

    fx4 sa[4];
    #pragma unroll
    for(int i=0;i<4;i++){ sa[i][0]=0.f; sa[i][1]=0.f; sa[i][2]=0.f; sa[i][3]=0.f; }
    #pragma unroll
    for(int kb=0;kb<4;kb++){
      #pragma unroll
      for(int i=0;i<4;i++){
        int row = 16*i + l16;
        s16x8 ak = *(const s16x8*)&Ks[row*128 + (((l4+4*kb)^(row&7))<<3)];
        sa[i] = __builtin_amdgcn_mfma_f32_16x16x32_bf16(ak, qf[kb], sa[i], 0,0,0);
      }
    }
    float pv[16]; float mloc=-1e30f;
    #pragma unroll
    for(int i=0;i<4;i++)
      #pragma unroll
      for(int r=0;r<4;r++){
        int kg = kt0 + 16*i + 4*l4 + r;
        float s = (kg<=qglob)? sa[i][r] : -1e30f;
        pv[i*4+r]=s; mloc=fmaxf(mloc,s);
      }
    mloc = fmaxf(mloc, __shfl_xor(mloc,16));
    mloc = fmaxf(mloc, __shfl_xor(mloc,32));
    float mnew = fmaxf(mrun,mloc);
    float alpha = __expf(mrun-mnew);
    float psum=0.f;
    #pragma unroll
    for(int z=0;z<16;z++){ pv[z]=__expf(pv[z]-mnew); psum+=pv[z]; }
    psum += __shfl_xor(psum,16); psum += __shfl_xor(psum,32);
    lrun = lrun*alpha + psum; mrun = mnew;
    #pragma unroll
    for(int t=0;t<4;t++){ ot[t][0]*=alpha; ot[t][1]*=alpha; ot[t][2]*=alpha; ot[t][3]*=alpha; }
    {
      unsigned short* pw = &Pl[wave][l16*72 + 4*l4];
      #pragma unroll
      for(int i=0;i<4;i++){
        *(unsigned int*)&pw[16*i]   = pk2(pv[i*4+0],pv[i*4+1]);
        *(unsigned int*)&pw[16*i+2] = pk2(pv[i*4+2],pv[i*4+3]);
      }
    }
    #pragma unroll
    for(int kb=0;kb<2;kb++){
      s16x8 pf = *(const s16x8*)&Pl[wave][l16*72 + kb*32 + l4*8];
      #pragma unroll
      for(int t=0;t<4;t++){
        s16x8 av = *(const s16x8*)&Vt[(16*t+l16)*72 + kb*32 + l4*8];
        ot[t] = __builtin_amdgcn_mfma_f32_16x16x32_bf16(av, pf, ot[t], 0,0,0);
      }
    }
  }

  float invl = 1.f/lrun;
  {
    unsigned short* pw = &Pl[wave][l16*72 + 4*l4];
    #pragma unroll
    for(int t=0;t<4;t++){
      *(unsigned int*)&pw[16*t]   = pk2(ot[t][0]*invl, ot[t][1]*invl);
      *(unsigned int*)&pw[16*t+2] = pk2(ot[t][2]*invl, ot[t][3]*invl);
    }
  }
  __syncthreads();
  #pragma unroll
  for(int it=0;it<4;it++){
    int idx = tid + it*256;
    int ee = idx>>4, dd = (idx&15)*4;
    float4 wv = *(const float4*)(Wo + h*4096 + ee*64 + dd);
    ushort4 w4; w4.x=f2bf(wv.x); w4.y=f2bf(wv.y); w4.z=f2bf(wv.z); w4.w=f2bf(wv.w);
    *(ushort4*)&Vt[ee*72 + dd] = w4;
  }
  __syncthreads();
  fx4 outT[4];
  #pragma unroll
  for(int t=0;t<4;t++){ outT[t][0]=0.f; outT[t][1]=0.f; outT[t][2]=0.f; outT[t][3]=0.f; }
  #pragma unroll
  for(int kb=0;kb<2;kb++){
    s16x8 of = *(const s16x8*)&Pl[wave][l16*72 + kb*32 + l4*8];
    #pragma unroll
    for(int t=0;t<4;t++){
      s16x8 aw = *(const s16x8*)&Vt[(16*t+l16)*72 + kb*32 + l4*8];
      outT[t] = __builtin_amdgcn_mfma_f32_16x16x32_bf16(aw, of, outT[t], 0,0,0);
    }
  }
  #pragma unroll
  for(int t=0;t<4;t++){
    size_t base = (size_t)qglob*D_ + h*64 + 16*t + 4*l4;
    float4 xv = *(const float4*)(x + base);
    float4 r;
    r.x = xv.x + outT[t][0]; r.y = xv.y + outT[t][1];
    r.z = xv.z + outT[t][2]; r.w = xv.w + outT[t][3];
    *(float4*)(x1+base) = r;
  }
}

// ---------------- gating: rmsnorm (writes y2) + router + noisy top-2 ----------------
__global__ __launch_bounds__(64) void k_gate(const float* __restrict__ x1, const float* __restrict__ Wr,
    const float* __restrict__ Wn, const float* __restrict__ r_bias, const float* __restrict__ noise_u,
    float* __restrict__ gates, int* __restrict__ topi, unsigned short* __restrict__ y2){
  int s = blockIdx.x, lane = threadIdx.x;
  const float* xr = x1 + (size_t)s*D_ + lane*16;
  float yv[16]; float ss=0.f;
  #pragma unroll
  for(int i=0;i<16;i+=4){
    float4 a = *(const float4*)(xr+i);
    yv[i]=a.x; yv[i+1]=a.y; yv[i+2]=a.z; yv[i+3]=a.w;
    ss += a.x*a.x+a.y*a.y+a.z*a.z+a.w*a.w;
  }
  #pragma unroll
  for(int o=1;o<64;o<<=1) ss += __shfl_xor(ss,o);
  float sc = rsqrtf(ss*(1.0f/D_) + 1e-6f);
  #pragma unroll
  for(int i=0;i<16;i++) yv[i]*=sc;
  {
    unsigned short* yo = y2 + (size_t)s*D_ + lane*16;
    ushort4 o0,o1,o2,o3;
    o0.x=f2bf(yv[0]); o0.y=f2bf(yv[1]); o0.z=f2bf(yv[2]); o0.w=f2bf(yv[3]);
    o1.x=f2bf(yv[4]); o1.y=f2bf(yv[5]); o1.z=f2bf(yv[6]); o1.w=f2bf(yv[7]);
    o2.x=f2bf(yv[8]); o2.y=f2bf(yv[9]); o2.z=f2bf(yv[10]); o2.w=f2bf(yv[11]);
    o3.x=f2bf(yv[12]); o3.y=f2bf(yv[13]); o3.z=f2bf(yv[14]); o3.w=f2bf(yv[15]);
    *(ushort4*)(yo)   = o0; *(ushort4*)(yo+4) = o1;
    *(ushort4*)(yo+8) = o2; *(ushort4*)(yo+12)= o3;
  }
  float lg[8], nz[8];
  #pragma unroll
  for(int e=0;e<8;e++){
    const float* wr = Wr + e*D_ + lane*16;
    const float* wn = Wn + e*D_ + lane*16;
    float a=0.f,b=0.f;
    #pragma unroll
    for(int i=0;i<16;i+=4){
      float4 w1 = *(const float4*)(wr+i); float4 w2 = *(const float4*)(wn+i);
      a += yv[i]*w1.x + yv[i+1]*w1.y + yv[i+2]*w1.z + yv[i+3]*w1.w;
      b += yv[i]*w2.x + yv[i+1]*w2.y + yv[i+2]*w2.z + yv[i+3]*w2.w;
    }
    lg[e]=a; nz[e]=b;
  }
  #pragma unroll
  for(int o=1;o<64;o<<=1){
    #pragma unroll
    for(int e=0;e<8;e++){ lg[e]+=__shfl_xor(lg[e],o); nz[e]+=__shfl_xor(nz[e],o); }
  }
  if(lane==0){
    float nl[8];
    for(int e=0;e<8;e++){
      float z = nz[e];
      float sp = (z>20.f)? z : log1pf(expf(z));
      nl[e] = noise_u[s*8+e]*sp + lg[e] + r_bias[e];
    }
    int i0=0; float v0=nl[0];
    for(int e=1;e<8;e++) if(nl[e]>v0){v0=nl[e];i0=e;}
    float v1=-1e30f; int i1=0;
    for(int e=0;e<8;e++) if(e!=i0 && nl[e]>v1){v1=nl[e];i1=e;}
    float ex = expf(v1-v0);
    gates[s*2]   = 1.f/(1.f+ex);
    gates[s*2+1] = ex/(1.f+ex);
    topi[s*2]=i0; topi[s*2+1]=i1;
  }
}

// ---------------- per-expert padded token lists (pad 128) ----------------
__global__ __launch_bounds__(256) void k_lists(const int* __restrict__ topi,
    int* __restrict__ offs, int* __restrict__ pair_tok, int* __restrict__ slot_of){
  __shared__ int tp[2048];
  __shared__ int cnt[8];
  __shared__ int off_s[9];
  int t = threadIdx.x;
  int wave = t>>6, lane = t&63;
  unsigned long long below = (lane==63)? 0xFFFFFFFFFFFFFFFFull>>1
                                       : ((1ull<<lane)-1ull);
  for(int i=t;i<2048;i+=256) tp[i]=topi[i];
  __syncthreads();
  #pragma unroll
  for(int sub=0;sub<2;sub++){
    int e = wave*2+sub;
    int c=0;
    for(int ch=0;ch<32;ch++) c += (tp[ch*64+lane]==e);
    #pragma unroll
    for(int o=1;o<64;o<<=1) c += __shfl_xor(c,o);
    if(lane==0) cnt[e]=c;
  }
  __syncthreads();
  if(t==0){
    int a=0;
    for(int e=0;e<8;e++){ off_s[e]=a; a += (cnt[e]+127)&~127; }
    off_s[8]=a;
    for(int e=0;e<9;e++) offs[e]=off_s[e];
  }
  __syncthreads();
  #pragma unroll
  for(int sub=0;sub<2;sub++){
    int e = wave*2+sub;
    int base = off_s[e];
    for(int ch=0;ch<32;ch++){
      int idx = ch*64+lane;
      bool pred = (tp[idx]==e);
      unsigned long long mask = __ballot(pred);
      if(pred){
        int slot = base + __popcll(mask & below);
        pair_tok[slot] = idx>>1;
        slot_of[idx] = slot;
      }
      base += __popcll(mask);
    }
    for(int slot=base+lane; slot<off_s[e+1]; slot+=64) pair_tok[slot]=0;
  }
}

// ---------------- transpose-convert: src f32 [e][R][C] -> dst bf16 [e][C][R] ----------------
__global__ __launch_bounds__(256) void k_cvt_t(const float* __restrict__ src,
    unsigned short* __restrict__ dst, int R, int C){
  __shared__ float ts[64][65];
  int e = blockIdx.z;
  int r0 = blockIdx.x*64, c0 = blockIdx.y*64;
  const float* s = src + (size_t)e*R*C;
  unsigned short* d = dst + (size_t)e*R*C;
  int t = threadIdx.x;
  #pragma unroll
  for(int it=0; it<4; it++){
    int flat = it*256+t;
    int r = flat>>4, cq = (flat&15)*4;
    float4 v = *(const float4*)(s + (size_t)(r0+r)*C + c0+cq);
    ts[r][cq]=v.x; ts[r][cq+1]=v.y; ts[r][cq+2]=v.z; ts[r][cq+3]=v.w;
  }
  __syncthreads();
  #pragma unroll
  for(int it=0; it<4; it++){
    int flat = it*256+t;
    int c = flat>>4, kq = (flat&15)*4;
    ushort4 o;
    o.x=f2bf(ts[kq][c]); o.y=f2bf(ts[kq+1][c]); o.z=f2bf(ts[kq+2][c]); o.w=f2bf(ts[kq+3][c]);
    *(ushort4*)(d + (size_t)(c0+c)*R + r0+kq) = o;
  }
}

// ---------------- FC1: single-buffer read-frags-first pipeline ----------------
__global__ __launch_bounds__(256) void k_fc1t(const unsigned short* __restrict__ y2,
    const int* __restrict__ pair_tok, const int* __restrict__ offs,
    const unsigned short* __restrict__ Bt, const float* __restrict__ bias1,
    unsigned short* __restrict__ hbuf){
  __shared__ unsigned short As[8192];   // 16 KB [row][64k], granule-swizzled
  __shared__ unsigned short Bs[8192];   // 16 KB
  __shared__ int sh_e;
  int tid=threadIdx.x, lane=tid&63, wv=tid>>6;
  int swz = xcd_swz(blockIdx.x, 768);
  int r0 = (swz % 24)*128, n0 = (swz / 24)*128;
  if(tid==0){ int e=-1; if(r0<offs[8]){e=0; while(offs[e+1]<=r0) e++;} sh_e=e; }
  __syncthreads();
  int e=sh_e; if(e<0) return;
  int rg = lane>>3;
  int sg = (lane&7)^(rg&7);
  const unsigned short* aptr[4];
  const unsigned short* bptr[4];
  #pragma unroll
  for(int c=0;c<4;c++){
    int ch = wv*4+c;
    int tok = pair_tok[r0 + ch*8 + rg];
    aptr[c] = y2 + (size_t)tok*D_ + sg*8;
    bptr[c] = Bt + (size_t)e*D_*F_ + (size_t)(n0 + ch*8 + rg)*D_ + sg*8;
  }
  int l16=lane&15, l4=lane>>4;
  int wm=wv>>1, wn=wv&1;
  fx4 acc[4][4];
  #pragma unroll
  for(int a0=0;a0<4;a0++)
    #pragma unroll
    for(int b0=0;b0<4;b0++){ acc[a0][b0][0]=0.f; acc[a0][b0][1]=0.f; acc[a0][b0][2]=0.f; acc[a0][b0][3]=0.f; }

  // prologue: stage tile 0
  #pragma unroll
  for(int c=0;c<4;c++){
    gld16(aptr[c], &As[(wv*4+c)*512]);
    gld16(bptr[c], &Bs[(wv*4+c)*512]);
  }

  for(int kt=0;kt<D_;kt+=64){
    asm volatile("s_waitcnt vmcnt(0)" ::: "memory");   // tile-t loads landed
    asm volatile("s_barrier" ::: "memory");
    // 1) read ALL tile-t fragments into registers
    s16x8 af[2][4], bf[2][4];
    #pragma unroll
    for(int kb=0;kb<2;kb++){
      #pragma unroll
      for(int mf=0;mf<4;mf++){
        int row = wm*64+mf*16+l16;
        af[kb][mf] = *(const s16x8*)&As[row*64 + (((kb*4+l4)^(row&7))*8)];
      }
      #pragma unroll
      for(int nf=0;nf<4;nf++){
        int col = wn*64+nf*16+l16;
        bf[kb][nf] = *(const s16x8*)&Bs[col*64 + (((kb*4+l4)^(col&7))*8)];
      }
    }
    // 2) all waves done reading LDS before overwrite
    asm volatile("s_waitcnt lgkmcnt(0)" ::: "memory");
    asm volatile("s_barrier" ::: "memory");
    // 3) issue tile-t+1 loads into the SAME buffer (fly across MFMA phase)
    if(kt+64<D_){
      #pragma unroll
      for(int c=0;c<4;c++){
        gld16(aptr[c]+kt+64, &As[(wv*4+c)*512]);
        gld16(bptr[c]+kt+64, &Bs[(wv*4+c)*512]);
      }
    }
    __builtin_amdgcn_sched_barrier(0);
    // 4) register-only MFMA phase
    __builtin_amdgcn_s_setprio(1);
    #pragma unroll
    for(int kb=0;kb<2;kb++)
      #pragma unroll
      for(int mf=0;mf<4;mf++)
        #pragma unroll
        for(int nf=0;nf<4;nf++)
          acc[mf][nf]=__builtin_amdgcn_mfma_f32_16x16x32_bf16(af[kb][mf],bf[kb][nf],acc[mf][nf],0,0,0);
    __builtin_amdgcn_s_setprio(0);
  }
  #pragma unroll
  for(int mf=0;mf<4;mf++)
    #pragma unroll
    for(int nf=0;nf<4;nf++){
      int gcol=n0+wn*64+nf*16+l16;
      float bias=bias1[e*F_+gcol];
      #pragma unroll
      for(int rgi=0;rgi<4;rgi++){
        int grow=r0+wm*64+mf*16+l4*4+rgi;
        float vv=acc[mf][nf][rgi]+bias;
        float g=0.5f*vv*(1.f+erff(vv*0.70710678118654752f));
        hbuf[(size_t)grow*F_+gcol]=f2bf(g);
      }
    }
}

// ---------------- FC2: single-buffer read-frags-first, split-K ----------------
__global__ __launch_bounds__(256) void k_fc2t(const unsigned short* __restrict__ hbuf,
    const int* __restrict__ offs, const unsigned short* __restrict__ Bt,
    const float* __restrict__ bias2, float* __restrict__ eo, int klen, int parts){
  __shared__ unsigned short As[8192];   // 16 KB
  __shared__ unsigned short Bs[4096];   // 8 KB
  __shared__ int sh_e;
  int tid=threadIdx.x, lane=tid&63, wv=tid>>6;
  int nwg = 384*parts;
  int swz = xcd_swz(blockIdx.x, nwg);
  int kz  = swz / 384;
  int rem = swz % 384;
  int r0 = (rem % 24)*128, n0 = (rem / 24)*64;
  int k0 = kz*klen;
  if(tid==0){ int e=-1; if(r0<offs[8]){e=0; while(offs[e+1]<=r0) e++;} sh_e=e; }
  __syncthreads();
  int e=sh_e; if(e<0) return;
  int rg = lane>>3;
  int sg = (lane&7)^(rg&7);
  const unsigned short* aptr[4];
  const unsigned short* bptr[2];
  #pragma unroll
  for(int c=0;c<4;c++){
    int ch = wv*4+c;
    aptr[c] = hbuf + (size_t)(r0 + ch*8 + rg)*F_ + k0 + sg*8;
  }
  #pragma unroll
  for(int c=0;c<2;c++){
    int ch = wv*2+c;
    bptr[c] = Bt + (size_t)e*F_*D_ + (size_t)(n0 + ch*8 + rg)*F_ + k0 + sg*8;
  }
  int l16=lane&15, l4=lane>>4;
  fx4 acc[2][4];
  #pragma unroll
  for(int a0=0;a0<2;a0++)
    #pragma unroll
    for(int b0=0;b0<4;b0++){ acc[a0][b0][0]=0.f; acc[a0][b0][1]=0.f; acc[a0][b0][2]=0.f; acc[a0][b0][3]=0.f; }

  #pragma unroll
  for(int c=0;c<4;c++) gld16(aptr[c], &As[(wv*4+c)*512]);
  #pragma unroll
  for(int c=0;c<2;c++) gld16(bptr[c], &Bs[(wv*2+c)*512]);

  for(int kt=0;kt<klen;kt+=64){
    asm volatile("s_waitcnt vmcnt(0)" ::: "memory");
    asm volatile("s_barrier" ::: "memory");
    s16x8 af[2][2], bf[2][4];
    #pragma unroll
    for(int kb=0;kb<2;kb++){
      #pragma unroll
      for(int mf=0;mf<2;mf++){
        int row = wv*32+mf*16+l16;
        af[kb][mf] = *(const s16x8*)&As[row*64 + (((kb*4+l4)^(row&7))*8)];
      }
      #pragma unroll
      for(int nf=0;nf<4;nf++){
        int col = nf*16+l16;
        bf[kb][nf] = *(const s16x8*)&Bs[col*64 + (((kb*4+l4)^(col&7))*8)];
      }
    }
    asm volatile("s_waitcnt lgkmcnt(0)" ::: "memory");
    asm volatile("s_barrier" ::: "memory");
    if(kt+64<klen){
      #pragma unroll
      for(int c=0;c<4;c++) gld16(aptr[c]+kt+64, &As[(wv*4+c)*512]);
      #pragma unroll
      for(int c=0;c<2;c++) gld16(bptr[c]+kt+64, &Bs[(wv*2+c)*512]);
    }
    __builtin_amdgcn_sched_barrier(0);
    __builtin_amdgcn_s_setprio(1);
    #pragma unroll
    for(int kb=0;kb<2;kb++)
      #pragma unroll
      for(int mf=0;mf<2;mf++)
        #pragma unroll
        for(int nf=0;nf<4;nf++)
          acc[mf][nf]=__builtin_amdgcn_mfma_f32_16x16x32_bf16(af[kb][mf],bf[kb][nf],acc[mf][nf],0,0,0);
    __builtin_amdgcn_s_setprio(0);
  }
  float* eop = eo + (size_t)kz*3072*D_;
  #pragma unroll
  for(int mf=0;mf<2;mf++)
    #pragma unroll
    for(int nf=0;nf<4;nf++){
      int gcol=n0+nf*16+l16;
      float bias=(kz==0)? bias2[e*D_+gcol] : 0.f;
      #pragma unroll
      for(int rgi=0;rgi<4;rgi++){
        int grow=r0+wv*32+mf*16+l4*4+rgi;
        eop[(size_t)grow*D_+gcol]=acc[mf][nf][rgi]+bias;
      }
    }
}

// ---------------- fallback FC kernels (round-6 proven) ----------------
__global__ __launch_bounds__(256) void k_fc1_fb(const unsigned short* __restrict__ y2,
    const int* __restrict__ pair_tok, const int* __restrict__ offs,
    const float* __restrict__ W1, const float* __restrict__ bias1,
    unsigned short* __restrict__ hbuf){
  __shared__ unsigned short As[4096];
  __shared__ unsigned short Bs[4096];
  __shared__ int sh_e;
  int tid=threadIdx.x;
  int r0=blockIdx.x*128, n0=blockIdx.y*128;
  if(tid==0){ int e=-1; if(r0<offs[8]){ e=0; while(offs[e+1]<=r0) e++; } sh_e=e; }
  __syncthreads();
  int e=sh_e; if(e<0) return;
  const float* Bsrc = W1 + (size_t)e*D_*F_;
  int r=tid&127, hf=tid>>7;
  int tok=pair_tok[r0+r];
  const unsigned short* Asrc = y2 + (size_t)tok*D_ + hf*16;
  int pk=tid>>5, pn=tid&31;
  int lane=tid&63, wvid=tid>>6;
  int wm=wvid>>1, wn=wvid&1;
  int l16=lane&15, l4=lane>>4;
  fx4 acc[4][4];
  #pragma unroll
  for(int a0=0;a0<4;a0++)
    #pragma unroll
    for(int b0=0;b0<4;b0++){ acc[a0][b0][0]=0.f; acc[a0][b0][1]=0.f; acc[a0][b0][2]=0.f; acc[a0][b0][3]=0.f; }
  for(int kt=0;kt<D_;kt+=32){
    uint4 av0=*(const uint4*)(Asrc+kt);
    uint4 av1=*(const uint4*)(Asrc+kt+8);
    const float* bp=Bsrc+(size_t)(kt+pk*4)*F_+n0+pn*4;
    float4 bv0=*(const float4*)(bp);
    float4 bv1=*(const float4*)(bp+F_);
    float4 bv2=*(const float4*)(bp+2*F_);
    float4 bv3=*(const float4*)(bp+3*F_);
    *(uint4*)&As[(hf*2)*1024 + r*8]=av0;
    *(uint4*)&As[(hf*2+1)*1024 + r*8]=av1;
    unsigned short c0[4]={f2bf(bv0.x),f2bf(bv0.y),f2bf(bv0.z),f2bf(bv0.w)};
    unsigned short c1[4]={f2bf(bv1.x),f2bf(bv1.y),f2bf(bv1.z),f2bf(bv1.w)};
    unsigned short c2[4]={f2bf(bv2.x),f2bf(bv2.y),f2bf(bv2.z),f2bf(bv2.w)};
    unsigned short c3[4]={f2bf(bv3.x),f2bf(bv3.y),f2bf(bv3.z),f2bf(bv3.w)};
    #pragma unroll
    for(int j2=0;j2<4;j2++){
      int col=pn*4+j2;
      int kb=(pk*4)^(((col>>2)&3)<<3);
      ushort4 wr;
      wr.x=c0[j2]; wr.y=c1[j2]; wr.z=c2[j2]; wr.w=c3[j2];
      *(ushort4*)&Bs[col*32+kb]=wr;
    }
    __syncthreads();
    s16x8 af[4],bf8[4];
    #pragma unroll
    for(int mf=0;mf<4;mf++){
      int rowl=wm*64+mf*16+l16;
      af[mf]=*(const s16x8*)&As[l4*1024+rowl*8];
    }
    #pragma unroll
    for(int nf=0;nf<4;nf++){
      int col=wn*64+nf*16+l16;
      int kb=(l4*8)^(((col>>2)&3)<<3);
      bf8[nf]=*(const s16x8*)&Bs[col*32+kb];
    }
    #pragma unroll
    for(int mf=0;mf<4;mf++)
      #pragma unroll
      for(int nf=0;nf<4;nf++)
        acc[mf][nf]=__builtin_amdgcn_mfma_f32_16x16x32_bf16(af[mf],bf8[nf],acc[mf][nf],0,0,0);
    __syncthreads();
  }
  #pragma unroll
  for(int mf=0;mf<4;mf++)
    #pragma unroll
    for(int nf=0;nf<4;nf++){
      int gcol=n0+wn*64+nf*16+l16;
      float bias=bias1[e*F_+gcol];
      #pragma unroll
      for(int rg=0;rg<4;rg++){
        int grow=r0+wm*64+mf*16+l4*4+rg;
        float vv=acc[mf][nf][rg]+bias;
        float g=0.5f*vv*(1.f+erff(vv*0.70710678118654752f));
        hbuf[(size_t)grow*F_+gcol]=f2bf(g);
      }
    }
}

__global__ __launch_bounds__(256) void k_fc2_fb(const unsigned short* __restrict__ hbuf,
    const int* __restrict__ offs, const float* __restrict__ W2,
    const float* __restrict__ bias2, float* __restrict__ eo){
  __shared__ unsigned short As[4096];
  __shared__ unsigned short Bs[2048];
  __shared__ int sh_e;
  int tid=threadIdx.x;
  int r0=blockIdx.x*128, n0=blockIdx.y*64;
  if(tid==0){ int e=-1; if(r0<offs[8]){ e=0; while(offs[e+1]<=r0) e++; } sh_e=e; }
  __syncthreads();
  int e=sh_e; if(e<0) return;
  const float* Bsrc=W2+(size_t)e*F_*D_;
  int r=tid&127, hf=tid>>7;
  const unsigned short* Asrc=hbuf+(size_t)(r0+r)*F_+hf*16;
  int pk=tid>>4, pn=tid&15;
  int lane=tid&63, wvid=tid>>6;
  int l16=lane&15, l4=lane>>4;
  fx4 acc[2][4];
  #pragma unroll
  for(int a0=0;a0<2;a0++)
    #pragma unroll
    for(int b0=0;b0<4;b0++){ acc[a0][b0][0]=0.f; acc[a0][b0][1]=0.f; acc[a0][b0][2]=0.f; acc[a0][b0][3]=0.f; }
  for(int kt=0;kt<F_;kt+=32){
    uint4 av0=*(const uint4*)(Asrc+kt);
    uint4 av1=*(const uint4*)(Asrc+kt+8);
    const float* bp=Bsrc+(size_t)(kt+pk*2)*D_+n0+pn*4;
    float4 bv0=*(const float4*)bp;
    float4 bv1=*(const float4*)(bp+D_);
    *(uint4*)&As[(hf*2)*1024+r*8]=av0;
    *(uint4*)&As[(hf*2+1)*1024+r*8]=av1;
    unsigned short c0[4]={f2bf(bv0.x),f2bf(bv0.y),f2bf(bv0.z),f2bf(bv0.w)};
    unsigned short c1[4]={f2bf(bv1.x),f2bf(bv1.y),f2bf(bv1.z),f2bf(bv1.w)};
    #pragma unroll
    for(int j2=0;j2<4;j2++){
      int col=pn*4+j2;
      int kb=(pk*2)^(((col>>2)&3)<<3);
      unsigned int pack=(unsigned int)c0[j2] | ((unsigned int)c1[j2]<<16);
      *(unsigned int*)&Bs[col*32+kb]=pack;
    }
    __syncthreads();
    s16x8 af[2],bf8[4];
    #pragma unroll
    for(int mf=0;mf<2;mf++){
      int rowl=wvid*32+mf*16+l16;
      af[mf]=*(const s16x8*)&As[l4*1024+rowl*8];
    }
    #pragma unroll
    for(int nf=0;nf<4;nf++){
      int col=nf*16+l16;
      int kb=(l4*8)^(((col>>2)&3)<<3);
      bf8[nf]=*(const s16x8*)&Bs[col*32+kb];
    }
    #pragma unroll
    for(int mf=0;mf<2;mf++)
      #pragma unroll
      for(int nf=0;nf<4;nf++)
        acc[mf][nf]=__builtin_amdgcn_mfma_f32_16x16x32_bf16(af[mf],bf8[nf],acc[mf][nf],0,0,0);
    __syncthreads();
  }
  #pragma unroll
  for(int mf=0;mf<2;mf++)
    #pragma unroll
    for(int nf=0;nf<4;nf++){
      int gcol=n0+nf*16+l16;
      float bias=bias2[e*D_+gcol];
      #pragma unroll
      for(int rg=0;rg<4;rg++){
        int grow=r0+wvid*32+mf*16+l4*4+rg;
        eo[(size_t)grow*D_+gcol]=acc[mf][nf][rg]+bias;
      }
    }
}

// ---------------- combine ----------------
__global__ __launch_bounds__(256) void k_combine(const float* __restrict__ x1, const float* __restrict__ eo,
    int parts, const float* __restrict__ gates, const int* __restrict__ slot_of, float* __restrict__ out){
  int s=blockIdx.x, t=threadIdx.x;
  float g0=gates[s*2], g1=gates[s*2+1];
  int a0=slot_of[s*2], a1=slot_of[s*2+1];
  float4 o=((const float4*)(x1+(size_t)s*D_))[t];
  for(int p=0;p<parts;p++){
    const float* ep = eo + (size_t)p*3072*D_;
    float4 e0=((const float4*)(ep+(size_t)a0*D_))[t];
    float4 e1=((const float4*)(ep+(size_t)a1*D_))[t];
    o.x+=g0*e0.x+g1*e1.x;
    o.y+=g0*e0.y+g1*e1.y;
    o.z+=g0*e0.z+g1*e1.z;
    o.w+=g0*e0.w+g1*e1.w;
  }
  ((float4*)(out+(size_t)s*D_))[t]=o;
}

extern "C" void kernel_launch(void* const* d_in, const int* in_sizes, int n_in,
                              void* d_out, int out_size, void* d_ws, size_t ws_size,
                              hipStream_t stream){
  (void)in_sizes; (void)n_in; (void)out_size;
  const float* x       = (const float*)d_in[0];
  const float* noise_u = (const float*)d_in[1];
  const float* Wdkv    = (const float*)d_in[2];
  const float* Wq      = (const float*)d_in[3];
  const float* Wuv     = (const float*)d_in[4];
  const float* Wuk     = (const float*)d_in[5];
  const float* Wk_rope = (const float*)d_in[6];
  const float* Wq_rope = (const float*)d_in[7];
  const float* bq_rope = (const float*)d_in[8];
  const float* Wo_head = (const float*)d_in[9];
  const float* Wr      = (const float*)d_in[10];
  const float* Wn      = (const float*)d_in[11];
  const float* r_bias  = (const float*)d_in[12];
  const float* W1      = (const float*)d_in[13];
  const float* b1      = (const float*)d_in[14];
  const float* W2      = (const float*)d_in[15];
  const float* b2      = (const float*)d_in[16];
  float* out           = (float*)d_out;

  char* w = (char*)d_ws;
  unsigned short* y    = (unsigned short*)(w);             // 2 MB
  unsigned short* kk   = (unsigned short*)(w + 2097152);   // 4 MB
  unsigned short* qq   = (unsigned short*)(w + 6291456);   // 4 MB
  unsigned short* vv   = (unsigned short*)(w + 10485760);  // 2 MB
  float* abs_t         = (float*)(w + 12582912);           // 256 KB
  float* wuvt          = (float*)(w + 12845056);           // 256 KB
  float* x1            = (float*)(w + 13107200);           // 4 MB
  unsigned short* y2   = (unsigned short*)(w + 17301504);  // 2 MB
  float* gates         = (float*)(w + 19398656);           // 8 KB
  int* topi            = (int*)(w + 19406848);             // 8 KB
  int* slot_of         = (int*)(w + 19415040);             // 8 KB
  int* offs            = (int*)(w + 19423232);             // 4 KB
  int* pair_tok        = (int*)(w + 19427328);             // 16 KB
  unsigned short* hbuf = (unsigned short*)(w + 19443712);  // 24 MB -> ends 44609536
  float* eo            = (float*)(w + 44609536);           // up to 4 x 12 MB

  const size_t NEED4 = 162050048ull;
  const size_t NEED2 = 136884224ull;
  int parts; unsigned short* Wt;
  if(ws_size >= NEED4){ parts = 4; Wt = (unsigned short*)(w + 94941184); }
  else if(ws_size >= NEED2){ parts = 2; Wt = (unsigned short*)(w + 69775360); }
  else { parts = 0; Wt = 0; }

  if(parts){
    k_cvt_t<<<dim3(16,64,8),256,0,stream>>>(W1, Wt, D_, F_);   // W1t [e][n=F][k=D]
  }
  k_rmsnorm<<<S_,256,0,stream>>>(x, y);
  k_prep<<<H_,256,0,stream>>>(Wq, Wuk, Wuv, abs_t, wuvt);
  k_proj_m<<<dim3(16,H_),256,0,stream>>>(y, abs_t, wuvt, Wdkv, Wk_rope, Wq_rope, bq_rope, kk, qq, vv);
  k_attn2<<<dim3(16,H_),256,0,stream>>>(qq, kk, vv, Wo_head, x, x1);
  k_gate<<<S_,64,0,stream>>>(x1, Wr, Wn, r_bias, noise_u, gates, topi, y2);
  k_lists<<<1,256,0,stream>>>(topi, offs, pair_tok, slot_of);
  if(parts){
    k_fc1t<<<768,256,0,stream>>>(y2, pair_tok, offs, Wt, b1, hbuf);
    k_cvt_t<<<dim3(64,16,8),256,0,stream>>>(W2, Wt, F_, D_);   // W2t [e][n=D][k=F]
    k_fc2t<<<384*parts,256,0,stream>>>(hbuf, offs, Wt, b2, eo, F_/parts, parts);
    k_combine<<<S_,256,0,stream>>>(x1, eo, parts, gates, slot_of, out);
  } else {
    k_fc1_fb<<<dim3(24,32),256,0,stream>>>(y2, pair_tok, offs, W1, b1, hbuf);
    k_fc2_fb<<<dim3(24,16),256,0,stream>>>(hbuf, offs, W2, b2, eo);
    k_combine<<<S_,256,0,stream>>>(x1, eo, 1, gates, slot_of, out);
  }
}